// Round 1
// 362.776 us; speedup vs baseline: 1.0743x; 1.0743x over previous
//
#include <hip/hip_runtime.h>

// Problem constants (match reference)
constexpr int NUM_CLASSES  = 100000;
constexpr int EMBED_DIM    = 512;
constexpr int BATCH        = 16384;
constexpr int CENTER_ELEMS = NUM_CLASSES * EMBED_DIM;   // 51,200,000
constexpr int NSLOTS       = 256;                        // loss partial slots
constexpr int KMAX         = 8;                          // per-class item list capacity
constexpr float UPDATE_SCALE = 0.05f;                    // (1 - ALPHA)
constexpr float INV_COUNT  = 1.0f / 8388608.0f;          // 1/(BATCH*EMBED_DIM) = 2^-23

typedef float f4 __attribute__((ext_vector_type(4)));

// ---------------- new path (K-item lists, no dup atomics) ----------------
// ws layout: counts[NUM_CLASSES] | items[NUM_CLASSES*KMAX] | partials[NSLOTS]
constexpr size_t WS_NEW = (size_t)NUM_CLASSES * 4
                        + (size_t)NUM_CLASSES * KMAX * 4
                        + (size_t)NSLOTS * 4;

// ---------------- old fast path requirement (kept as middle tier) --------
constexpr size_t WS_OLD = (size_t)NUM_CLASSES * 8 + NSLOTS * 4;

__global__ void zero_ws_kernel(int* __restrict__ counts, float* __restrict__ partials) {
    int g = blockIdx.x * blockDim.x + threadIdx.x;
    if (g < NUM_CLASSES) counts[g] = 0;
    if (g < NSLOTS) partials[g] = 0.0f;
}

// histogram + per-class item list (first KMAX items recorded exactly)
__global__ void hist_kernel(const int* __restrict__ labels,
                            int* __restrict__ counts,
                            int* __restrict__ items) {
    int b = blockIdx.x * blockDim.x + threadIdx.x;
    if (b < BATCH) {
        int l = labels[b];
        int r = atomicAdd(&counts[l], 1);
        if (r < KMAX) items[l * KMAX + r] = b;
    }
}

// Two classes per 256-thread block. Each half-block (128 threads) owns one
// class row: load center (NT), fold all cnt<=KMAX items' updates exactly
// (deterministic sum, no atomics on out), accumulate loss partial.
// Store path: dst row is out+1+c*512 (4B misaligned) -> stage both rows in
// LDS shifted by one element so 255 lanes emit aligned 16B NT stores.
__global__ __launch_bounds__(256) void fused_rows_kernel(
        const float* __restrict__ features,
        const float* __restrict__ centers,
        const int*   __restrict__ counts,
        const int*   __restrict__ items,
        float* __restrict__ out,            // out[0]=loss, out+1 = new_centers
        float* __restrict__ partials) {
    const int t    = threadIdx.x;
    const int half = t >> 7;                 // 0 or 1
    const int ts   = t & 127;
    const int c    = blockIdx.x * 2 + half;
    const int cnt  = counts[c];

    const f4 c4 = __builtin_nontemporal_load(
        (const f4*)(centers + (size_t)c * EMBED_DIM) + ts);
    f4 n4 = c4;

    if (cnt > 0 && cnt <= KMAX) {
        f4 s; s.x = 0.f; s.y = 0.f; s.z = 0.f; s.w = 0.f;
        float local = 0.0f;
        for (int i = 0; i < cnt; ++i) {
            const int b = items[c * KMAX + i];
            const f4 f = __builtin_nontemporal_load(
                (const f4*)(features + (size_t)b * EMBED_DIM) + ts);
            float dx = f.x - c4.x;
            float dy = f.y - c4.y;
            float dz = f.z - c4.z;
            float dw = f.w - c4.w;
            s.x += dx; s.y += dy; s.z += dz; s.w += dw;
            local += dx * dx + dy * dy + dz * dz + dw * dw;
        }
        n4.x = fmaf(UPDATE_SCALE, s.x, c4.x);
        n4.y = fmaf(UPDATE_SCALE, s.y, c4.y);
        n4.z = fmaf(UPDATE_SCALE, s.z, c4.z);
        n4.w = fmaf(UPDATE_SCALE, s.w, c4.w);
        #pragma unroll
        for (int off = 32; off > 0; off >>= 1)
            local += __shfl_down(local, off, 64);
        if ((t & 63) == 0)
            atomicAdd(&partials[(c * 2 + (ts >> 6)) & (NSLOTS - 1)], local);
    }
    // cnt > KMAX (P ~ 2e-8): write plain copy; overflow_kernel applies deltas.

    __shared__ float row[2 * EMBED_DIM];
    ((f4*)row)[t] = n4;                      // row[half*512 + ts*4 ..]
    __syncthreads();

    const size_t R0 = (size_t)blockIdx.x * (2 * EMBED_DIM);
    if (t < 255) {
        // out[R0+4+4t+k] = newrows[3+4t+k]
        f4 o;
        o.x = row[4 * t + 3];
        o.y = row[4 * t + 4];
        o.z = row[4 * t + 5];
        o.w = row[4 * t + 6];
        __builtin_nontemporal_store(o, (f4*)(out + R0 + 4) + t);
    } else {
        out[R0 + 1] = row[0];
        out[R0 + 2] = row[1];
        out[R0 + 3] = row[2];
        out[R0 + 2 * EMBED_DIM] = row[2 * EMBED_DIM - 1];
    }
}

// Correctness net for classes with cnt > KMAX (never taken for this data).
// Thread = (item, 64-float segment); inactive threads cost 2 loads.
__global__ __launch_bounds__(256) void overflow_kernel(
        const float* __restrict__ features,
        const int*   __restrict__ labels,
        const float* __restrict__ centers,
        const int*   __restrict__ counts,
        float* __restrict__ out,
        float* __restrict__ partials) {
    const int b = blockIdx.x * blockDim.x + threadIdx.x;
    if (b >= BATCH) return;
    const int l = labels[b];
    if (counts[l] <= KMAX) return;
    const int seg = blockIdx.y;              // 0..7
    const float* f  = features + (size_t)b * EMBED_DIM + seg * 64;
    const float* cr = centers  + (size_t)l * EMBED_DIM + seg * 64;
    float* nrow = out + 1 + (size_t)l * EMBED_DIM + seg * 64;
    float local = 0.0f;
    for (int j = 0; j < 64; ++j) {
        float d = f[j] - cr[j];
        local += d * d;
        atomicAdd(nrow + j, UPDATE_SCALE * d);
    }
    atomicAdd(&partials[(b * 8 + seg) & (NSLOTS - 1)], local);
}

__global__ __launch_bounds__(64) void finalize_loss_kernel(
        const float* __restrict__ partials,
        float* __restrict__ out) {
    float v = 0.0f;
    #pragma unroll
    for (int k = 0; k < NSLOTS / 64; ++k)
        v += partials[threadIdx.x + k * 64];
    #pragma unroll
    for (int off = 32; off > 0; off >>= 1)
        v += __shfl_down(v, off, 64);
    if (threadIdx.x == 0)
        out[0] = v * INV_COUNT;
}

// ---------------- old fast path (middle tier, proven correct) ----------------

__global__ void hist1_kernel(const int* __restrict__ labels,
                             int* __restrict__ counts,
                             int* __restrict__ itemof) {
    int b = blockIdx.x * blockDim.x + threadIdx.x;
    if (b < BATCH) {
        int l = labels[b];
        atomicAdd(&counts[l], 1);
        itemof[l] = b;   // unique writer when count==1 (the only case read)
    }
}

__global__ __launch_bounds__(128) void fused_rows1_kernel(
        const float* __restrict__ features,
        const float* __restrict__ centers,
        const int*   __restrict__ counts,
        const int*   __restrict__ itemof,
        float* __restrict__ out,
        float* __restrict__ partials) {
    const int c = blockIdx.x;
    const int t = threadIdx.x;
    const int cnt = counts[c];

    const float4 c4 = ((const float4*)(centers + (size_t)c * EMBED_DIM))[t];
    float4 n4 = c4;

    __shared__ float row[EMBED_DIM];

    if (cnt == 1) {
        const int b = itemof[c];
        const float4 f4v = ((const float4*)(features + (size_t)b * EMBED_DIM))[t];
        float4 d;
        d.x = f4v.x - c4.x;
        d.y = f4v.y - c4.y;
        d.z = f4v.z - c4.z;
        d.w = f4v.w - c4.w;
        n4.x = fmaf(UPDATE_SCALE, d.x, c4.x);
        n4.y = fmaf(UPDATE_SCALE, d.y, c4.y);
        n4.z = fmaf(UPDATE_SCALE, d.z, c4.z);
        n4.w = fmaf(UPDATE_SCALE, d.w, c4.w);
        float local = d.x * d.x + d.y * d.y + d.z * d.z + d.w * d.w;
        #pragma unroll
        for (int off = 32; off > 0; off >>= 1)
            local += __shfl_down(local, off, 64);
        if ((t & 63) == 0)
            atomicAdd(&partials[(c * 2 + (t >> 6)) & (NSLOTS - 1)], local);
    }

    ((float4*)row)[t] = n4;
    __syncthreads();

    const size_t R = (size_t)c * EMBED_DIM;
    if (t < 127) {
        float4 o;
        o.x = row[4 * t + 3];
        o.y = row[4 * t + 4];
        o.z = row[4 * t + 5];
        o.w = row[4 * t + 6];
        ((float4*)(out + R + 4))[t] = o;
    } else {
        out[R + 1] = row[0];
        out[R + 2] = row[1];
        out[R + 3] = row[2];
        out[R + EMBED_DIM] = row[EMBED_DIM - 1];
    }
}

__global__ __launch_bounds__(128) void dup_update_kernel(
        const float* __restrict__ features,
        const int*   __restrict__ labels,
        const float* __restrict__ centers,
        const int*   __restrict__ counts,
        float* __restrict__ out,
        float* __restrict__ partials) {
    const int b = blockIdx.x;
    const int l = labels[b];
    if (counts[l] < 2) return;
    const int t = threadIdx.x;

    const float4 f4v = ((const float4*)(features + (size_t)b * EMBED_DIM))[t];
    const float4 c4 = ((const float4*)(centers + (size_t)l * EMBED_DIM))[t];
    float4 d;
    d.x = f4v.x - c4.x;
    d.y = f4v.y - c4.y;
    d.z = f4v.z - c4.z;
    d.w = f4v.w - c4.w;

    float* nrow = out + 1 + (size_t)l * EMBED_DIM + (size_t)t * 4;
    atomicAdd(nrow + 0, UPDATE_SCALE * d.x);
    atomicAdd(nrow + 1, UPDATE_SCALE * d.y);
    atomicAdd(nrow + 2, UPDATE_SCALE * d.z);
    atomicAdd(nrow + 3, UPDATE_SCALE * d.w);

    float local = d.x * d.x + d.y * d.y + d.z * d.z + d.w * d.w;
    #pragma unroll
    for (int off = 32; off > 0; off >>= 1)
        local += __shfl_down(local, off, 64);
    if ((t & 63) == 0)
        atomicAdd(&partials[(b * 2 + (t >> 6)) & (NSLOTS - 1)], local);
}

// ---------------- R1 fallback path (proven correct) ----------------

__global__ void copy_centers_kernel(const float* __restrict__ src,
                                    float* __restrict__ dst,
                                    float* __restrict__ ws_partials) {
    int gid = blockIdx.x * blockDim.x + threadIdx.x;
    if (gid < NSLOTS) ws_partials[gid] = 0.0f;
    int stride = gridDim.x * blockDim.x;
    for (int i = gid; i < CENTER_ELEMS; i += stride) dst[i] = src[i];
}

__global__ __launch_bounds__(128) void update_kernel(
        const float* __restrict__ features,
        const int*   __restrict__ labels,
        const float* __restrict__ centers,
        float* __restrict__ out,
        float* __restrict__ ws_partials) {
    const int b = blockIdx.x;
    const int label = labels[b];
    const int t = threadIdx.x;
    const float4 f = ((const float4*)(features + (size_t)b * EMBED_DIM))[t];
    const float4 c = ((const float4*)(centers + (size_t)label * EMBED_DIM))[t];
    float4 d;
    d.x = f.x - c.x; d.y = f.y - c.y; d.z = f.z - c.z; d.w = f.w - c.w;
    float* nrow = out + 1 + (size_t)label * EMBED_DIM + (size_t)t * 4;
    atomicAdd(nrow + 0, UPDATE_SCALE * d.x);
    atomicAdd(nrow + 1, UPDATE_SCALE * d.y);
    atomicAdd(nrow + 2, UPDATE_SCALE * d.z);
    atomicAdd(nrow + 3, UPDATE_SCALE * d.w);
    float local = d.x * d.x + d.y * d.y + d.z * d.z + d.w * d.w;
    #pragma unroll
    for (int off = 32; off > 0; off >>= 1)
        local += __shfl_down(local, off, 64);
    if ((t & 63) == 0)
        atomicAdd(&ws_partials[(b * 2 + (t >> 6)) & (NSLOTS - 1)], local);
}

// ---------------- launcher ----------------

extern "C" void kernel_launch(void* const* d_in, const int* in_sizes, int n_in,
                              void* d_out, int out_size, void* d_ws, size_t ws_size,
                              hipStream_t stream) {
    const float* features = (const float*)d_in[0];
    const int*   labels   = (const int*)d_in[1];
    const float* centers  = (const float*)d_in[2];
    float* out = (float*)d_out;

    if (ws_size >= WS_NEW) {
        int*   counts   = (int*)d_ws;
        int*   items    = counts + NUM_CLASSES;
        float* partials = (float*)(items + (size_t)NUM_CLASSES * KMAX);

        zero_ws_kernel<<<(NUM_CLASSES + 255) / 256, 256, 0, stream>>>(counts, partials);
        hist_kernel<<<(BATCH + 255) / 256, 256, 0, stream>>>(labels, counts, items);
        fused_rows_kernel<<<NUM_CLASSES / 2, 256, 0, stream>>>(features, centers, counts,
                                                               items, out, partials);
        overflow_kernel<<<dim3(BATCH / 256, 8), 256, 0, stream>>>(features, labels, centers,
                                                                  counts, out, partials);
        finalize_loss_kernel<<<1, 64, 0, stream>>>(partials, out);
    } else if (ws_size >= WS_OLD) {
        int*   counts   = (int*)d_ws;
        int*   itemof   = counts + NUM_CLASSES;
        float* partials = (float*)(itemof + NUM_CLASSES);

        zero_ws_kernel<<<(NUM_CLASSES + 255) / 256, 256, 0, stream>>>(counts, partials);
        hist1_kernel<<<(BATCH + 255) / 256, 256, 0, stream>>>(labels, counts, itemof);
        fused_rows1_kernel<<<NUM_CLASSES, 128, 0, stream>>>(features, centers, counts,
                                                            itemof, out, partials);
        dup_update_kernel<<<BATCH, 128, 0, stream>>>(features, labels, centers,
                                                     counts, out, partials);
        finalize_loss_kernel<<<1, 64, 0, stream>>>(partials, out);
    } else {
        float* partials = (float*)d_ws;
        copy_centers_kernel<<<8192, 256, 0, stream>>>(centers, out + 1, partials);
        update_kernel<<<BATCH, 128, 0, stream>>>(features, labels, centers, out, partials);
        finalize_loss_kernel<<<1, 64, 0, stream>>>(partials, out);
    }
}